// Round 4
// baseline (135.871 us; speedup 1.0000x reference)
//
#include <hip/hip_runtime.h>

#define D 128
#define LOG2E 1.4426950408889634f
#define LN2   0.6931471805599453f

// Kernel 1: find segment boundaries in sorted seg_ids -> seg_start[B+1]
__global__ void seg_bounds_kernel(const int* __restrict__ seg_ids,
                                  int* __restrict__ seg_start,
                                  int T, int B) {
    int t = blockIdx.x * blockDim.x + threadIdx.x;
    if (t >= T) return;
    if (t == 0) {
        seg_start[0] = 0;
    } else if (seg_ids[t] != seg_ids[t - 1]) {
        seg_start[seg_ids[t]] = t;
    }
    if (t == T - 1) seg_start[B] = T;
}

// Phase A: logits[t] = dot(graph_embed[seg_ids[t]], tpl_embedding[cand_idx[t]]).
// Half-wave (32 lanes x float4 = 512B row) per candidate; 4-way unrolled
// grid-stride: 8 row-loads in flight per wave before any shuffle consume,
// 4 independent butterfly chains interleaved to hide lgkm latency.
__global__ __launch_bounds__(256) void logits_kernel(
    const float* __restrict__ graph_embed,
    const float* __restrict__ tpl_embedding,
    const int* __restrict__ cand_idx,
    const int* __restrict__ seg_ids,
    float* __restrict__ logits,
    int T)
{
    const int sl  = threadIdx.x & 31;                              // lane in half-wave
    const int hw  = (blockIdx.x * blockDim.x + threadIdx.x) >> 5;  // half-wave id
    const int nhw = (gridDim.x * blockDim.x) >> 5;

    for (int t0 = hw; t0 < T; t0 += 4 * nhw) {
        int  t[4];
        bool vld[4];
        #pragma unroll
        for (int j = 0; j < 4; ++j) {
            const int tj = t0 + j * nhw;
            vld[j] = (tj < T);
            t[j]   = vld[j] ? tj : t0;
        }

        int c[4], s[4];
        #pragma unroll
        for (int j = 0; j < 4; ++j) { c[j] = cand_idx[t[j]]; s[j] = seg_ids[t[j]]; }

        float4 x[4], g[4];
        #pragma unroll
        for (int j = 0; j < 4; ++j)
            x[j] = ((const float4*)(tpl_embedding + (size_t)c[j] * D))[sl];
        #pragma unroll
        for (int j = 0; j < 4; ++j)
            g[j] = ((const float4*)(graph_embed + (size_t)s[j] * D))[sl];

        float p[4];
        #pragma unroll
        for (int j = 0; j < 4; ++j)
            p[j] = fmaf(g[j].x, x[j].x,
                   fmaf(g[j].y, x[j].y,
                   fmaf(g[j].z, x[j].z, g[j].w * x[j].w)));

        #pragma unroll
        for (int off = 16; off >= 1; off >>= 1) {
            #pragma unroll
            for (int j = 0; j < 4; ++j)
                p[j] += __shfl_xor(p[j], off);
        }

        if (sl == 0) {
            #pragma unroll
            for (int j = 0; j < 4; ++j)
                if (vld[j]) logits[t[j]] = p[j];
        }
    }
}

// Phase B: one wave per segment. Lane-per-candidate online softmax (64
// independent (m,s) chains), butterfly merge, target read directly.
__global__ __launch_bounds__(64) void seg_reduce_kernel(
    const float* __restrict__ logits,
    const int* __restrict__ seg_start,
    const int* __restrict__ target_pos,
    float* __restrict__ out)
{
    const int b    = blockIdx.x;
    const int lane = threadIdx.x;
    const int start = seg_start[b];
    const int end   = seg_start[b + 1];

    float m = -3.0e38f;  // running max (base-2 domain); finite sentinel avoids inf-inf
    float s = 0.0f;

    for (int t = start + lane; t < end; t += 64) {
        const float x = logits[t] * LOG2E;
        if (x <= m) {
            s += exp2f(x - m);
        } else {
            s = fmaf(s, exp2f(m - x), 1.0f);
            m = x;
        }
    }

    #pragma unroll
    for (int off = 32; off >= 1; off >>= 1) {
        const float m2 = __shfl_xor(m, off);
        const float s2 = __shfl_xor(s, off);
        const float M  = fmaxf(m, m2);
        s = s * exp2f(m - M) + s2 * exp2f(m2 - M);
        m = M;
    }

    if (lane == 0) {
        const float tl = logits[target_pos[b]] * LOG2E;
        out[b] = (tl - m - log2f(s)) * LN2;
    }
}

extern "C" void kernel_launch(void* const* d_in, const int* in_sizes, int n_in,
                              void* d_out, int out_size, void* d_ws, size_t ws_size,
                              hipStream_t stream) {
    const float* graph_embed   = (const float*)d_in[0];
    const float* tpl_embedding = (const float*)d_in[1];
    const int*   cand_idx      = (const int*)d_in[2];
    const int*   seg_ids       = (const int*)d_in[3];
    const int*   target_pos    = (const int*)d_in[4];
    float*       out           = (float*)d_out;

    const int B = in_sizes[0] / D;   // 8192
    const int T = in_sizes[2];       // 524288

    // ws layout: seg_start[B+1] ints, then logits[T] floats
    int*   seg_start = (int*)d_ws;
    float* logits    = (float*)d_ws + (((B + 1) + 63) & ~63);

    seg_bounds_kernel<<<(T + 255) / 256, 256, 0, stream>>>(seg_ids, seg_start, T, B);

    // 2048 blocks x 256 threads; each half-wave handles ~32 candidates via
    // the 4-way unrolled grid-stride loop (exactly 8 iterations at T=524288).
    logits_kernel<<<2048, 256, 0, stream>>>(graph_embed, tpl_embedding,
                                            cand_idx, seg_ids, logits, T);

    seg_reduce_kernel<<<B, 64, 0, stream>>>(logits, seg_start, target_pos, out);
}